// Round 4
// baseline (189.909 us; speedup 1.0000x reference)
//
#include <hip/hip_runtime.h>
#include <hip/hip_bf16.h>

// SpectralConv2d: B=8, CIN=COUT=32, N=4096, modes 32x x 31y (u_ft only needs y 0..15)
// Complex-K GEMM formulation:
//   u_ft[c,x](y) = sum_k A_y[c,k]*B[k,j]   k=2n+comp, j=2x+comp
//     A_y = u .* conj(E2in_y)  (built per chunk), B = conj(E1in) (pre-packed, swizzled)
//   Y[c,n] = sum_y Re( (sum_j Apre_y[c,j]*Bg[j,n]) * E2out[n,y] )
//
// ws (u32 slots), 18.0 MB total:
//   E2in  [8][16][4096]            : 524288    (aliased by A_pre after uft)
//   B_pre [8][64ch][64j][64n]swz   : 2097152   (aliased by E1out+E2out after uft)
//   P     [8s][8b][16y][32c][64j]  : 2097152 f32

#define NPTS 4096
#define TDIM 128
#define TWO_PI 6.283185307179586f

typedef __attribute__((ext_vector_type(8))) short bf16x8;
typedef __attribute__((ext_vector_type(4))) float f32x4;
typedef unsigned int u32;
typedef unsigned short u16;

__device__ __forceinline__ u32 pack2(float a, float b) {
  __hip_bfloat162 h = __float22bfloat162_rn(make_float2(a, b));  // v_cvt_pk_bf16_f32
  u32 r; __builtin_memcpy(&r, &h, 4); return r;
}
__device__ __forceinline__ float bflo(u32 u) { return __uint_as_float(u << 16); }
__device__ __forceinline__ float bfhi(u32 u) { return __uint_as_float(u & 0xFFFF0000u); }

__device__ __forceinline__ void async16(void* lds, const void* g) {
  __builtin_amdgcn_global_load_lds(
      (const __attribute__((address_space(1))) u32*)g,
      (__attribute__((address_space(3))) u32*)lds, 16, 0, 0);
}

// ---------------------------------------------------------------------------
// prep1: E2in (y 0..15, k2y=y) + B_pre (conj(E1in), swizzled LDS image).
__global__ __launch_bounds__(256) void prep1_kernel(
    const float* __restrict__ x_in, u32* __restrict__ E2in, u32* __restrict__ B_pre) {
  const int bid = blockIdx.x;              // 512
  const int b = bid & 7, ntile = bid >> 3; // 0..63
  const int tid = threadIdx.x;
  const int nl = tid & 63, task = tid >> 6;
  const int n = ntile * 64 + nl;
  float2 xv = *(const float2*)&x_in[(size_t)(b * NPTS + n) * 2];
  if (task < 2) {
    #pragma unroll
    for (int k = 0; k < 8; ++k) {
      int y = task * 8 + k;                          // 0..15 -> k2y = y
      float th = TWO_PI * xv.y * (float)y;
      float s, c; __sincosf(th, &s, &c);
      E2in[((b * 16 + y) << 12) + n] = pack2(c, s);
    }
  } else {
    char* base = (char*)(B_pre + (size_t)(b * 64 + ntile) * 4096);
    #pragma unroll
    for (int k = 0; k < 16; ++k) {
      int x = (task - 2) * 16 + k;
      float k1x = (x < 16) ? (float)x : (float)(x - 32);
      float th = TWO_PI * xv.x * k1x;
      float s, c; __sincosf(th, &s, &c);
      int r0 = 2 * x, r1 = 2 * x + 1;
      // conj(e1): B[2x][2n]=c, B[2x][2n+1]=s ; B[2x+1][2n]=-s, B[2x+1][2n+1]=c
      *(u32*)(base + r0 * 256 + ((4 * nl) ^ ((r0 & 7) << 4))) = pack2(c, s);
      *(u32*)(base + r1 * 256 + ((4 * nl) ^ ((r1 & 7) << 4))) = pack2(-s, c);
    }
  }
}

// ---------------------------------------------------------------------------
// prep2 (after uft, overwrites B_pre region): E1out + E2out cis tables.
__global__ __launch_bounds__(256) void prep2_kernel(
    const float* __restrict__ x_out, u32* __restrict__ E1out, u32* __restrict__ E2out) {
  const int bid = blockIdx.x;              // 512
  const int b = bid & 7, ntile = bid >> 3;
  const int tid = threadIdx.x;
  const int nl = tid & 63, task = tid >> 6;
  const int n = ntile * 64 + nl;
  float2 xv = *(const float2*)&x_out[(size_t)(b * NPTS + n) * 2];
  if (task < 2) {
    int cnt = task ? 15 : 16;
    for (int k = 0; k < cnt; ++k) {
      int y = task * 16 + k;                         // 0..30
      float k2y = (y < 16) ? (float)y : (float)(y - 31);
      float th = TWO_PI * xv.y * k2y;
      float s, c; __sincosf(th, &s, &c);
      E2out[((b * 32 + y) << 12) + n] = pack2(c, s);
    }
  } else {
    #pragma unroll
    for (int k = 0; k < 16; ++k) {
      int x = (task - 2) * 16 + k;
      float k1x = (x < 16) ? (float)x : (float)(x - 32);
      float th = TWO_PI * xv.x * k1x;
      float s, c; __sincosf(th, &s, &c);
      E1out[((b * 32 + x) << 12) + n] = pack2(c, s);
    }
  }
}

// ---------------------------------------------------------------------------
// uft: grid 512 = (b, yp 0..7, s 0..7). Per block: y={2yp,2yp+1}, n-range s*512,
// 8 chunks of 64n (K=128). B via global_load_lds from pre-swizzled B_pre.
__global__ __launch_bounds__(256, 4) void uft_kernel(
    const float* __restrict__ u, const u32* __restrict__ E2in,
    const u32* __restrict__ B_pre, float* __restrict__ P) {
  const int bid = blockIdx.x;
  const int b = bid & 7;                   // XCD pin
  const int inner = bid >> 3;
  const int yp = inner & 7;
  const int s = inner >> 3;
  const int tid = threadIdx.x;
  const int lane = tid & 63, wv = tid >> 6;

  __shared__ __align__(16) u16 A0s[32 * 128];   // [c][k] rows 256B, swizzled
  __shared__ __align__(16) u16 A1s[32 * 128];
  __shared__ __align__(16) u16 Bs[64 * 128];    // [j][k] rows 256B, swizzled

  const int y0 = 2 * yp, y1 = 2 * yp + 1;
  const int colw = lane & 15, kq = lane >> 4;
  const int brow = wv * 16 + colw;
  const int c = tid >> 3;                  // A-build row
  const int n8 = (tid & 7) * 8;

  f32x4 acc00 = {0,0,0,0}, acc01 = {0,0,0,0}, acc10 = {0,0,0,0}, acc11 = {0,0,0,0};

  float4 pu[2]; uint4 pea[2], peb[2];
  auto load_regs = [&](int ch) {
    int nb = s * 512 + ch * 64;
    const float4* up = (const float4*)&u[(size_t)(b * 32 + c) * NPTS + nb + n8];
    pu[0] = up[0]; pu[1] = up[1];
    const uint4* ea = (const uint4*)&E2in[((b * 16 + y0) << 12) + nb + n8];
    pea[0] = ea[0]; pea[1] = ea[1];
    const uint4* eb = (const uint4*)&E2in[((b * 16 + y1) << 12) + nb + n8];
    peb[0] = eb[0]; peb[1] = eb[1];
  };
  load_regs(0);

  for (int ch = 0; ch < 8; ++ch) {
    __syncthreads();
    // async-stage B chunk (16KB): linear LDS <- pre-swizzled global
    {
      const u32* src = B_pre + (size_t)(b * 64 + s * 8 + ch) * 4096 + wv * 1024 + lane * 4;
      u16* dst = Bs + wv * 2048;
      #pragma unroll
      for (int r = 0; r < 4; ++r) async16(dst + r * 512, src + r * 256);
    }
    // pack A_y = u .* conj(E2) from prefetched regs
    {
      float uu[8] = {pu[0].x, pu[0].y, pu[0].z, pu[0].w, pu[1].x, pu[1].y, pu[1].z, pu[1].w};
      u32 ea[8] = {pea[0].x,pea[0].y,pea[0].z,pea[0].w,pea[1].x,pea[1].y,pea[1].z,pea[1].w};
      u32 eb[8] = {peb[0].x,peb[0].y,peb[0].z,peb[0].w,peb[1].x,peb[1].y,peb[1].z,peb[1].w};
      u32 wa[8], wb[8];
      #pragma unroll
      for (int i = 0; i < 8; ++i) {
        wa[i] = pack2(uu[i] * bflo(ea[i]), -(uu[i] * bfhi(ea[i])));
        wb[i] = pack2(uu[i] * bflo(eb[i]), -(uu[i] * bfhi(eb[i])));
      }
      const int swz = (c & 7) << 4;
      char* a0p = (char*)A0s + c * 256;
      char* a1p = (char*)A1s + c * 256;
      *(uint4*)(a0p + ((4 * n8) ^ swz))      = make_uint4(wa[0], wa[1], wa[2], wa[3]);
      *(uint4*)(a0p + ((4 * n8 + 16) ^ swz)) = make_uint4(wa[4], wa[5], wa[6], wa[7]);
      *(uint4*)(a1p + ((4 * n8) ^ swz))      = make_uint4(wb[0], wb[1], wb[2], wb[3]);
      *(uint4*)(a1p + ((4 * n8 + 16) ^ swz)) = make_uint4(wb[4], wb[5], wb[6], wb[7]);
    }
    if (ch < 7) load_regs(ch + 1);   // overlaps the barrier drain window
    __syncthreads();

    #pragma unroll
    for (int ks = 0; ks < 4; ++ks) {
      int kb = ks * 64 + kq * 16;
      const int swzc = (colw & 7) << 4;
      bf16x8 bb  = *(bf16x8*)((char*)Bs  + brow * 256 + (kb ^ ((brow & 7) << 4)));
      bf16x8 a00 = *(bf16x8*)((char*)A0s + colw * 256 + (kb ^ swzc));
      bf16x8 a01 = *(bf16x8*)((char*)A0s + (colw + 16) * 256 + (kb ^ swzc));
      bf16x8 a10 = *(bf16x8*)((char*)A1s + colw * 256 + (kb ^ swzc));
      bf16x8 a11 = *(bf16x8*)((char*)A1s + (colw + 16) * 256 + (kb ^ swzc));
      acc00 = __builtin_amdgcn_mfma_f32_16x16x32_bf16(a00, bb, acc00, 0, 0, 0);
      acc01 = __builtin_amdgcn_mfma_f32_16x16x32_bf16(a01, bb, acc01, 0, 0, 0);
      acc10 = __builtin_amdgcn_mfma_f32_16x16x32_bf16(a10, bb, acc10, 0, 0, 0);
      acc11 = __builtin_amdgcn_mfma_f32_16x16x32_bf16(a11, bb, acc11, 0, 0, 0);
    }
  }

  // P[s][b][y][c][j]
  size_t base0 = (((size_t)s * 8 + b) * 16 + y0) * 2048;
  size_t base1 = (((size_t)s * 8 + b) * 16 + y1) * 2048;
  #pragma unroll
  for (int r = 0; r < 4; ++r) {
    int cr0 = kq * 4 + r, cr1 = cr0 + 16;
    P[base0 + cr0 * 64 + brow] = acc00[r];
    P[base0 + cr1 * 64 + brow] = acc01[r];
    P[base1 + cr0 * 64 + brow] = acc10[r];
    P[base1 + cr1 * 64 + brow] = acc11[r];
  }
}

// ---------------------------------------------------------------------------
// apply: 8-way split-K reduce + emb conditioning + Hermitian extension,
// writes bf16-packed A_pre[b][y0..30][c][j=2X+comp] (u32 = one complex).
__global__ __launch_bounds__(512) void apply_kernel(
    const float* __restrict__ t, const float* __restrict__ w_freq,
    const float* __restrict__ b_freq, const float* __restrict__ w1,
    const float* __restrict__ w2, const float* __restrict__ P,
    u32* __restrict__ A32) {
  const int x = blockIdx.x, b = blockIdx.y;
  const int tid = threadIdx.x;
  const int m1 = x & 15, sel = x >> 4;

  __shared__ float uf_s[32][16][2];
  __shared__ float emb_s[16][2];

  for (int e = tid; e < 1024; e += 512) {
    int i = e >> 5, r = e & 31, yy = r >> 1, comp = r & 1;
    size_t base = (((size_t)(b * 16 + yy)) * 32 + i) * 64 + 2 * x + comp;
    float sacc = 0.f;
    #pragma unroll
    for (int ss = 0; ss < 8; ++ss) sacc += P[base + (size_t)ss * 262144];
    uf_s[i][yy][comp] = sacc;
  }
  if (tid < 32) {
    int yy = tid >> 1, p = tid & 1;
    int jj = ((m1 * 16 + yy) * 2 + sel) * 2 + p;
    float sv = b_freq[jj];
    for (int k = 0; k < TDIM; ++k) sv += t[b * TDIM + k] * w_freq[k * 1024 + jj];
    emb_s[yy][p] = sv;
  }
  __syncthreads();

  int o = tid >> 4, y = tid & 15;
  const float* wsel = sel ? w2 : w1;
  float fr = 0.f, fi = 0.f;
  #pragma unroll 4
  for (int i = 0; i < 32; ++i) {
    float2 w = *(const float2*)&wsel[(size_t)(((i * 32 + o) * 16 + m1) * 16 + y) * 2];
    float ur = uf_s[i][y][0], ui = uf_s[i][y][1];
    fr += ur * w.x - ui * w.y;
    fi += ur * w.y + ui * w.x;
  }
  float er = emb_s[y][0], ei = emb_s[y][1];
  float orr = fr * er - fi * ei;
  float oii = fr * ei + fi * er;
  A32[((b * 31 + y) * 32 + o) * 32 + x] = pack2(orr, oii);
  if (y > 0)
    A32[((b * 31 + (31 - y)) * 32 + o) * 32 + (31 - x)] = pack2(orr, -oii);
}

// ---------------------------------------------------------------------------
// inv: grid 512 = (b, nt 0..63). B (E1out-derived) in regs for whole y-loop;
// A-frags direct from global (L1-hot, prefetched); no barriers in y-loop.
__global__ __launch_bounds__(256, 4) void inv_kernel(
    const u32* __restrict__ A32, const u32* __restrict__ E1out,
    const u32* __restrict__ E2out, float* __restrict__ Y) {
  const int bid = blockIdx.x;
  const int b = bid & 7, nt = bid >> 3;
  const int n0 = nt * 64;
  const int tid = threadIdx.x;
  const int lane = tid & 63, wv = tid >> 6;
  const int colw = lane & 15, kq = lane >> 4;

  __shared__ __align__(16) u16 Bgr[64 * 64];   // [n][k=2X+comp] rows 128B, swizzled
  __shared__ __align__(16) u16 Bgi[64 * 64];
  __shared__ u32 e2s[31 * 64];

  {
    const int n = tid & 63, Xg = tid >> 6;
    #pragma unroll
    for (int i = 0; i < 8; ++i) {
      int X = Xg * 8 + i;
      u32 e = E1out[((b * 32 + X) << 12) + n0 + n];
      float c1 = bflo(e), s1 = bfhi(e);
      int byt = (4 * X) ^ ((n & 7) << 4);
      *(u32*)((char*)Bgr + n * 128 + byt) = pack2(c1, -s1);
      *(u32*)((char*)Bgi + n * 128 + byt) = pack2(s1, c1);
    }
  }
  for (int idx = tid; idx < 1984; idx += 256) {
    int y = idx >> 6, n = idx & 63;
    e2s[idx] = E2out[((b * 32 + y) << 12) + n0 + n];
  }
  __syncthreads();

  const int brow = wv * 16 + colw;
  bf16x8 bgr[2], bgi[2];
  #pragma unroll
  for (int ks = 0; ks < 2; ++ks) {
    int kb = ks * 64 + kq * 16;
    bgr[ks] = *(bf16x8*)((char*)Bgr + brow * 128 + (kb ^ ((brow & 7) << 4)));
    bgi[ks] = *(bf16x8*)((char*)Bgi + brow * 128 + (kb ^ ((brow & 7) << 4)));
  }

  f32x4 Y0 = {0,0,0,0}, Y1 = {0,0,0,0};
  const u32* Abase = A32 + (size_t)b * 31 * 1024;

  bf16x8 af0, af1, af2, af3, nf0, nf1, nf2, nf3;
  auto loadA = [&](int y, bf16x8& f0, bf16x8& f1, bf16x8& f2, bf16x8& f3) {
    const u32* p = Abase + y * 1024;
    f0 = *(bf16x8*)(p + colw * 32 + kq * 4);
    f1 = *(bf16x8*)(p + colw * 32 + 16 + kq * 4);
    f2 = *(bf16x8*)(p + (colw + 16) * 32 + kq * 4);
    f3 = *(bf16x8*)(p + (colw + 16) * 32 + 16 + kq * 4);
  };
  loadA(0, af0, af1, af2, af3);

  for (int y = 0; y < 31; ++y) {
    if (y < 30) loadA(y + 1, nf0, nf1, nf2, nf3);
    f32x4 z = {0,0,0,0};
    f32x4 gr0 = __builtin_amdgcn_mfma_f32_16x16x32_bf16(af0, bgr[0], z, 0, 0, 0);
    gr0 = __builtin_amdgcn_mfma_f32_16x16x32_bf16(af1, bgr[1], gr0, 0, 0, 0);
    f32x4 gr1 = __builtin_amdgcn_mfma_f32_16x16x32_bf16(af2, bgr[0], z, 0, 0, 0);
    gr1 = __builtin_amdgcn_mfma_f32_16x16x32_bf16(af3, bgr[1], gr1, 0, 0, 0);
    f32x4 gi0 = __builtin_amdgcn_mfma_f32_16x16x32_bf16(af0, bgi[0], z, 0, 0, 0);
    gi0 = __builtin_amdgcn_mfma_f32_16x16x32_bf16(af1, bgi[1], gi0, 0, 0, 0);
    f32x4 gi1 = __builtin_amdgcn_mfma_f32_16x16x32_bf16(af2, bgi[0], z, 0, 0, 0);
    gi1 = __builtin_amdgcn_mfma_f32_16x16x32_bf16(af3, bgi[1], gi1, 0, 0, 0);
    u32 e2 = e2s[y * 64 + brow];
    float c2 = bflo(e2), s2 = bfhi(e2);
    #pragma unroll
    for (int r = 0; r < 4; ++r) {
      Y0[r] += gr0[r] * c2 - gi0[r] * s2;
      Y1[r] += gr1[r] * c2 - gi1[r] * s2;
    }
    af0 = nf0; af1 = nf1; af2 = nf2; af3 = nf3;
  }

  int n = n0 + brow;
  #pragma unroll
  for (int r = 0; r < 4; ++r) {
    Y[(size_t)(b * 32 + kq * 4 + r) * NPTS + n] = Y0[r];
    Y[(size_t)(b * 32 + kq * 4 + r + 16) * NPTS + n] = Y1[r];
  }
}

// ---------------------------------------------------------------------------
extern "C" void kernel_launch(void* const* d_in, const int* in_sizes, int n_in,
                              void* d_out, int out_size, void* d_ws, size_t ws_size,
                              hipStream_t stream) {
  const float* u      = (const float*)d_in[0];
  const float* x_in   = (const float*)d_in[1];
  const float* x_out  = (const float*)d_in[2];
  const float* t      = (const float*)d_in[3];
  const float* w_freq = (const float*)d_in[4];
  const float* b_freq = (const float*)d_in[5];
  const float* w1     = (const float*)d_in[6];
  const float* w2     = (const float*)d_in[7];
  float* Y = (float*)d_out;

  u32* E2in  = (u32*)d_ws;                 // 524288
  u32* B_pre = E2in + 524288;              // 2097152
  u32* E1out = B_pre;                      // alias (prep2 runs after uft)
  u32* E2out = B_pre + 1048576;
  float* P   = (float*)(B_pre + 2097152);  // 2097152 f32
  u32* A32   = E2in;                       // alias (apply runs after uft)

  prep1_kernel<<<512, 256, 0, stream>>>(x_in, E2in, B_pre);
  uft_kernel<<<512, 256, 0, stream>>>(u, E2in, B_pre, P);
  prep2_kernel<<<512, 256, 0, stream>>>(x_out, E1out, E2out);
  apply_kernel<<<dim3(32, 8), 512, 0, stream>>>(t, w_freq, b_freq, w1, w2, P, A32);
  inv_kernel<<<512, 256, 0, stream>>>(A32, E1out, E2out, Y);
}

// Round 6
// 108.300 us; speedup vs baseline: 1.7535x; 1.7535x over previous
//
#include <hip/hip_runtime.h>
#include <hip/hip_bf16.h>

// SpectralConv2d: B=8, CIN=COUT=32, N=4096, modes 32x x 31y (u_ft only needs y 0..15)
// Complex-K GEMM formulation:
//   u_ft[c,x](y) = sum_k A_y[c,k]*B[k,j]   k=2n+comp, j=2x+comp
//     A_y = u .* conj(E2in_y)  (built per chunk), B = conj(E1in) (pre-packed, swizzled)
//   Y[c,n] = sum_y Re( (sum_j Apre_y[c,j]*Bg[j,n]) * E2out[n,y] )
//
// NOTE (r5 lesson): Bs staging is reg->ds_write, NOT global_load_lds. The DMA's
// LDS write is vmcnt-tracked; the pre-MFMA __syncthreads drain did not provably
// cover it (r5 failed 0.0607 when lean, r4 "passed" only because spills made it
// slow). ds_write is lgkmcnt-tracked -> barrier provably covers it.
//
// ws (u32 slots), 18.0 MB total:
//   E2in  [8][16][4096]            : 524288    (aliased by A_pre after uft)
//   B_pre [8][64ch][64j][64n]swz   : 2097152   (aliased by E1out+E2out after uft)
//   P     [8s][8b][16y][32c][64j]  : 2097152 f32

#define NPTS 4096
#define TDIM 128
#define TWO_PI 6.283185307179586f

typedef __attribute__((ext_vector_type(8))) short bf16x8;
typedef __attribute__((ext_vector_type(4))) float f32x4;
typedef unsigned int u32;
typedef unsigned short u16;

__device__ __forceinline__ u32 pack2(float a, float b) {
  __hip_bfloat162 h = __float22bfloat162_rn(make_float2(a, b));  // v_cvt_pk_bf16_f32
  u32 r; __builtin_memcpy(&r, &h, 4); return r;
}
__device__ __forceinline__ float bflo(u32 u) { return __uint_as_float(u << 16); }
__device__ __forceinline__ float bfhi(u32 u) { return __uint_as_float(u & 0xFFFF0000u); }

// ---------------------------------------------------------------------------
// prep1: E2in (y 0..15, k2y=y) + B_pre (conj(E1in), swizzled LDS image).
__global__ __launch_bounds__(256) void prep1_kernel(
    const float* __restrict__ x_in, u32* __restrict__ E2in, u32* __restrict__ B_pre) {
  const int bid = blockIdx.x;              // 512
  const int b = bid & 7, ntile = bid >> 3; // 0..63
  const int tid = threadIdx.x;
  const int nl = tid & 63, task = tid >> 6;
  const int n = ntile * 64 + nl;
  float2 xv = *(const float2*)&x_in[(size_t)(b * NPTS + n) * 2];
  if (task < 2) {
    #pragma unroll
    for (int k = 0; k < 8; ++k) {
      int y = task * 8 + k;                          // 0..15 -> k2y = y
      float th = TWO_PI * xv.y * (float)y;
      float s, c; __sincosf(th, &s, &c);
      E2in[((b * 16 + y) << 12) + n] = pack2(c, s);
    }
  } else {
    char* base = (char*)(B_pre + (size_t)(b * 64 + ntile) * 4096);
    #pragma unroll
    for (int k = 0; k < 16; ++k) {
      int x = (task - 2) * 16 + k;
      float k1x = (x < 16) ? (float)x : (float)(x - 32);
      float th = TWO_PI * xv.x * k1x;
      float s, c; __sincosf(th, &s, &c);
      int r0 = 2 * x, r1 = 2 * x + 1;
      // conj(e1): B[2x][2n]=c, B[2x][2n+1]=s ; B[2x+1][2n]=-s, B[2x+1][2n+1]=c
      *(u32*)(base + r0 * 256 + ((4 * nl) ^ ((r0 & 7) << 4))) = pack2(c, s);
      *(u32*)(base + r1 * 256 + ((4 * nl) ^ ((r1 & 7) << 4))) = pack2(-s, c);
    }
  }
}

// ---------------------------------------------------------------------------
// prep2 (after uft, overwrites B_pre region): E1out + E2out cis tables.
__global__ __launch_bounds__(256) void prep2_kernel(
    const float* __restrict__ x_out, u32* __restrict__ E1out, u32* __restrict__ E2out) {
  const int bid = blockIdx.x;              // 512
  const int b = bid & 7, ntile = bid >> 3;
  const int tid = threadIdx.x;
  const int nl = tid & 63, task = tid >> 6;
  const int n = ntile * 64 + nl;
  float2 xv = *(const float2*)&x_out[(size_t)(b * NPTS + n) * 2];
  if (task < 2) {
    int cnt = task ? 15 : 16;
    for (int k = 0; k < cnt; ++k) {
      int y = task * 16 + k;                         // 0..30
      float k2y = (y < 16) ? (float)y : (float)(y - 31);
      float th = TWO_PI * xv.y * k2y;
      float s, c; __sincosf(th, &s, &c);
      E2out[((b * 32 + y) << 12) + n] = pack2(c, s);
    }
  } else {
    #pragma unroll
    for (int k = 0; k < 16; ++k) {
      int x = (task - 2) * 16 + k;
      float k1x = (x < 16) ? (float)x : (float)(x - 32);
      float th = TWO_PI * xv.x * k1x;
      float s, c; __sincosf(th, &s, &c);
      E1out[((b * 32 + x) << 12) + n] = pack2(c, s);
    }
  }
}

// ---------------------------------------------------------------------------
// uft: grid 512 = (b, yp 0..7, s 0..7). Per block: y={2yp,2yp+1}, n-range s*512,
// 8 chunks of 64n (K=128). B staged reg->ds_write from pre-swizzled B_pre.
// launch_bounds(256,2): VGPR cap 256 (no r4 spill), 2 blocks/CU matches grid.
__global__ __launch_bounds__(256, 2) void uft_kernel(
    const float* __restrict__ u, const u32* __restrict__ E2in,
    const u32* __restrict__ B_pre, float* __restrict__ P) {
  const int bid = blockIdx.x;
  const int b = bid & 7;                   // XCD pin
  const int inner = bid >> 3;
  const int yp = inner & 7;
  const int s = inner >> 3;
  const int tid = threadIdx.x;
  const int lane = tid & 63, wv = tid >> 6;

  __shared__ __align__(16) u16 A0s[32 * 128];   // [c][k] rows 256B, swizzled
  __shared__ __align__(16) u16 A1s[32 * 128];
  __shared__ __align__(16) u16 Bs[64 * 128];    // [j][k] rows 256B, swizzled

  const int y0 = 2 * yp, y1 = 2 * yp + 1;
  const int colw = lane & 15, kq = lane >> 4;
  const int brow = wv * 16 + colw;
  const int c = tid >> 3;                  // A-build row
  const int n8 = (tid & 7) * 8;

  f32x4 acc00 = {0,0,0,0}, acc01 = {0,0,0,0}, acc10 = {0,0,0,0}, acc11 = {0,0,0,0};

  float4 pu[2]; uint4 pea[2], peb[2]; uint4 pb[4];
  auto load_regs = [&](int ch) {
    int nb = s * 512 + ch * 64;
    const float4* up = (const float4*)&u[(size_t)(b * 32 + c) * NPTS + nb + n8];
    pu[0] = up[0]; pu[1] = up[1];
    const uint4* ea = (const uint4*)&E2in[((b * 16 + y0) << 12) + nb + n8];
    pea[0] = ea[0]; pea[1] = ea[1];
    const uint4* eb = (const uint4*)&E2in[((b * 16 + y1) << 12) + nb + n8];
    peb[0] = eb[0]; peb[1] = eb[1];
    // B image chunk: wave-contiguous rows (byte layout identical to LDS dest)
    const u32* bp = B_pre + (size_t)(b * 64 + s * 8 + ch) * 4096 + wv * 1024 + lane * 4;
    #pragma unroll
    for (int r = 0; r < 4; ++r) pb[r] = *(const uint4*)(bp + r * 256);
  };
  load_regs(0);

  for (int ch = 0; ch < 8; ++ch) {
    __syncthreads();   // previous MFMA reads done before restaging

    // stage B: 4x ds_write_b128, same placement the DMA used (1KB/wave rows)
    {
      char* dst = (char*)Bs + wv * 4096 + lane * 16;
      #pragma unroll
      for (int r = 0; r < 4; ++r) *(uint4*)(dst + r * 1024) = pb[r];
    }
    // pack A_y = u .* conj(E2) from prefetched regs
    {
      float uu[8] = {pu[0].x, pu[0].y, pu[0].z, pu[0].w, pu[1].x, pu[1].y, pu[1].z, pu[1].w};
      u32 ea[8] = {pea[0].x,pea[0].y,pea[0].z,pea[0].w,pea[1].x,pea[1].y,pea[1].z,pea[1].w};
      u32 eb[8] = {peb[0].x,peb[0].y,peb[0].z,peb[0].w,peb[1].x,peb[1].y,peb[1].z,peb[1].w};
      u32 wa[8], wb[8];
      #pragma unroll
      for (int i = 0; i < 8; ++i) {
        wa[i] = pack2(uu[i] * bflo(ea[i]), -(uu[i] * bfhi(ea[i])));
        wb[i] = pack2(uu[i] * bflo(eb[i]), -(uu[i] * bfhi(eb[i])));
      }
      const int swz = (c & 7) << 4;
      char* a0p = (char*)A0s + c * 256;
      char* a1p = (char*)A1s + c * 256;
      *(uint4*)(a0p + ((4 * n8) ^ swz))      = make_uint4(wa[0], wa[1], wa[2], wa[3]);
      *(uint4*)(a0p + ((4 * n8 + 16) ^ swz)) = make_uint4(wa[4], wa[5], wa[6], wa[7]);
      *(uint4*)(a1p + ((4 * n8) ^ swz))      = make_uint4(wb[0], wb[1], wb[2], wb[3]);
      *(uint4*)(a1p + ((4 * n8 + 16) ^ swz)) = make_uint4(wb[4], wb[5], wb[6], wb[7]);
    }
    if (ch < 7) load_regs(ch + 1);   // prefetch next chunk (hidden under MFMA)
    __syncthreads();

    #pragma unroll
    for (int ks = 0; ks < 4; ++ks) {
      int kb = ks * 64 + kq * 16;
      const int swzc = (colw & 7) << 4;
      bf16x8 bb  = *(bf16x8*)((char*)Bs  + brow * 256 + (kb ^ ((brow & 7) << 4)));
      bf16x8 a00 = *(bf16x8*)((char*)A0s + colw * 256 + (kb ^ swzc));
      bf16x8 a01 = *(bf16x8*)((char*)A0s + (colw + 16) * 256 + (kb ^ swzc));
      bf16x8 a10 = *(bf16x8*)((char*)A1s + colw * 256 + (kb ^ swzc));
      bf16x8 a11 = *(bf16x8*)((char*)A1s + (colw + 16) * 256 + (kb ^ swzc));
      acc00 = __builtin_amdgcn_mfma_f32_16x16x32_bf16(a00, bb, acc00, 0, 0, 0);
      acc01 = __builtin_amdgcn_mfma_f32_16x16x32_bf16(a01, bb, acc01, 0, 0, 0);
      acc10 = __builtin_amdgcn_mfma_f32_16x16x32_bf16(a10, bb, acc10, 0, 0, 0);
      acc11 = __builtin_amdgcn_mfma_f32_16x16x32_bf16(a11, bb, acc11, 0, 0, 0);
    }
  }

  // P[s][b][y][c][j]
  size_t base0 = (((size_t)s * 8 + b) * 16 + y0) * 2048;
  size_t base1 = (((size_t)s * 8 + b) * 16 + y1) * 2048;
  #pragma unroll
  for (int r = 0; r < 4; ++r) {
    int cr0 = kq * 4 + r, cr1 = cr0 + 16;
    P[base0 + cr0 * 64 + brow] = acc00[r];
    P[base0 + cr1 * 64 + brow] = acc01[r];
    P[base1 + cr0 * 64 + brow] = acc10[r];
    P[base1 + cr1 * 64 + brow] = acc11[r];
  }
}

// ---------------------------------------------------------------------------
// apply: 8-way split-K reduce + emb conditioning + Hermitian extension,
// writes bf16-packed A_pre[b][y0..30][c][j=2X+comp] (u32 = one complex).
__global__ __launch_bounds__(512) void apply_kernel(
    const float* __restrict__ t, const float* __restrict__ w_freq,
    const float* __restrict__ b_freq, const float* __restrict__ w1,
    const float* __restrict__ w2, const float* __restrict__ P,
    u32* __restrict__ A32) {
  const int x = blockIdx.x, b = blockIdx.y;
  const int tid = threadIdx.x;
  const int m1 = x & 15, sel = x >> 4;

  __shared__ float uf_s[32][16][2];
  __shared__ float emb_s[16][2];

  for (int e = tid; e < 1024; e += 512) {
    int i = e >> 5, r = e & 31, yy = r >> 1, comp = r & 1;
    size_t base = (((size_t)(b * 16 + yy)) * 32 + i) * 64 + 2 * x + comp;
    float sacc = 0.f;
    #pragma unroll
    for (int ss = 0; ss < 8; ++ss) sacc += P[base + (size_t)ss * 262144];
    uf_s[i][yy][comp] = sacc;
  }
  if (tid < 32) {
    int yy = tid >> 1, p = tid & 1;
    int jj = ((m1 * 16 + yy) * 2 + sel) * 2 + p;
    float sv = b_freq[jj];
    for (int k = 0; k < TDIM; ++k) sv += t[b * TDIM + k] * w_freq[k * 1024 + jj];
    emb_s[yy][p] = sv;
  }
  __syncthreads();

  int o = tid >> 4, y = tid & 15;
  const float* wsel = sel ? w2 : w1;
  float fr = 0.f, fi = 0.f;
  #pragma unroll 4
  for (int i = 0; i < 32; ++i) {
    float2 w = *(const float2*)&wsel[(size_t)(((i * 32 + o) * 16 + m1) * 16 + y) * 2];
    float ur = uf_s[i][y][0], ui = uf_s[i][y][1];
    fr += ur * w.x - ui * w.y;
    fi += ur * w.y + ui * w.x;
  }
  float er = emb_s[y][0], ei = emb_s[y][1];
  float orr = fr * er - fi * ei;
  float oii = fr * ei + fi * er;
  A32[((b * 31 + y) * 32 + o) * 32 + x] = pack2(orr, oii);
  if (y > 0)
    A32[((b * 31 + (31 - y)) * 32 + o) * 32 + (31 - x)] = pack2(orr, -oii);
}

// ---------------------------------------------------------------------------
// inv: grid 512 = (b, nt 0..63). B (E1out-derived) in regs for whole y-loop;
// A-frags direct from global (L2-hot, prefetched); no barriers in y-loop.
__global__ __launch_bounds__(256, 2) void inv_kernel(
    const u32* __restrict__ A32, const u32* __restrict__ E1out,
    const u32* __restrict__ E2out, float* __restrict__ Y) {
  const int bid = blockIdx.x;
  const int b = bid & 7, nt = bid >> 3;
  const int n0 = nt * 64;
  const int tid = threadIdx.x;
  const int lane = tid & 63, wv = tid >> 6;
  const int colw = lane & 15, kq = lane >> 4;

  __shared__ __align__(16) u16 Bgr[64 * 64];   // [n][k=2X+comp] rows 128B, swizzled
  __shared__ __align__(16) u16 Bgi[64 * 64];
  __shared__ u32 e2s[31 * 64];

  {
    const int n = tid & 63, Xg = tid >> 6;
    #pragma unroll
    for (int i = 0; i < 8; ++i) {
      int X = Xg * 8 + i;
      u32 e = E1out[((b * 32 + X) << 12) + n0 + n];
      float c1 = bflo(e), s1 = bfhi(e);
      int byt = (4 * X) ^ ((n & 7) << 4);
      *(u32*)((char*)Bgr + n * 128 + byt) = pack2(c1, -s1);
      *(u32*)((char*)Bgi + n * 128 + byt) = pack2(s1, c1);
    }
  }
  for (int idx = tid; idx < 1984; idx += 256) {
    int y = idx >> 6, n = idx & 63;
    e2s[idx] = E2out[((b * 32 + y) << 12) + n0 + n];
  }
  __syncthreads();

  const int brow = wv * 16 + colw;
  bf16x8 bgr[2], bgi[2];
  #pragma unroll
  for (int ks = 0; ks < 2; ++ks) {
    int kb = ks * 64 + kq * 16;
    bgr[ks] = *(bf16x8*)((char*)Bgr + brow * 128 + (kb ^ ((brow & 7) << 4)));
    bgi[ks] = *(bf16x8*)((char*)Bgi + brow * 128 + (kb ^ ((brow & 7) << 4)));
  }

  f32x4 Y0 = {0,0,0,0}, Y1 = {0,0,0,0};
  const u32* Abase = A32 + (size_t)b * 31 * 1024;

  bf16x8 af0, af1, af2, af3, nf0, nf1, nf2, nf3;
  auto loadA = [&](int y, bf16x8& f0, bf16x8& f1, bf16x8& f2, bf16x8& f3) {
    const u32* p = Abase + y * 1024;
    f0 = *(bf16x8*)(p + colw * 32 + kq * 4);
    f1 = *(bf16x8*)(p + colw * 32 + 16 + kq * 4);
    f2 = *(bf16x8*)(p + (colw + 16) * 32 + kq * 4);
    f3 = *(bf16x8*)(p + (colw + 16) * 32 + 16 + kq * 4);
  };
  loadA(0, af0, af1, af2, af3);

  for (int y = 0; y < 31; ++y) {
    if (y < 30) loadA(y + 1, nf0, nf1, nf2, nf3);
    f32x4 z = {0,0,0,0};
    f32x4 gr0 = __builtin_amdgcn_mfma_f32_16x16x32_bf16(af0, bgr[0], z, 0, 0, 0);
    gr0 = __builtin_amdgcn_mfma_f32_16x16x32_bf16(af1, bgr[1], gr0, 0, 0, 0);
    f32x4 gr1 = __builtin_amdgcn_mfma_f32_16x16x32_bf16(af2, bgr[0], z, 0, 0, 0);
    gr1 = __builtin_amdgcn_mfma_f32_16x16x32_bf16(af3, bgr[1], gr1, 0, 0, 0);
    f32x4 gi0 = __builtin_amdgcn_mfma_f32_16x16x32_bf16(af0, bgi[0], z, 0, 0, 0);
    gi0 = __builtin_amdgcn_mfma_f32_16x16x32_bf16(af1, bgi[1], gi0, 0, 0, 0);
    f32x4 gi1 = __builtin_amdgcn_mfma_f32_16x16x32_bf16(af2, bgi[0], z, 0, 0, 0);
    gi1 = __builtin_amdgcn_mfma_f32_16x16x32_bf16(af3, bgi[1], gi1, 0, 0, 0);
    u32 e2 = e2s[y * 64 + brow];
    float c2 = bflo(e2), s2 = bfhi(e2);
    #pragma unroll
    for (int r = 0; r < 4; ++r) {
      Y0[r] += gr0[r] * c2 - gi0[r] * s2;
      Y1[r] += gr1[r] * c2 - gi1[r] * s2;
    }
    af0 = nf0; af1 = nf1; af2 = nf2; af3 = nf3;
  }

  int n = n0 + brow;
  #pragma unroll
  for (int r = 0; r < 4; ++r) {
    Y[(size_t)(b * 32 + kq * 4 + r) * NPTS + n] = Y0[r];
    Y[(size_t)(b * 32 + kq * 4 + r + 16) * NPTS + n] = Y1[r];
  }
}

// ---------------------------------------------------------------------------
extern "C" void kernel_launch(void* const* d_in, const int* in_sizes, int n_in,
                              void* d_out, int out_size, void* d_ws, size_t ws_size,
                              hipStream_t stream) {
  const float* u      = (const float*)d_in[0];
  const float* x_in   = (const float*)d_in[1];
  const float* x_out  = (const float*)d_in[2];
  const float* t      = (const float*)d_in[3];
  const float* w_freq = (const float*)d_in[4];
  const float* b_freq = (const float*)d_in[5];
  const float* w1     = (const float*)d_in[6];
  const float* w2     = (const float*)d_in[7];
  float* Y = (float*)d_out;

  u32* E2in  = (u32*)d_ws;                 // 524288
  u32* B_pre = E2in + 524288;              // 2097152
  u32* E1out = B_pre;                      // alias (prep2 runs after uft)
  u32* E2out = B_pre + 1048576;
  float* P   = (float*)(B_pre + 2097152);  // 2097152 f32
  u32* A32   = E2in;                       // alias (apply runs after uft)

  prep1_kernel<<<512, 256, 0, stream>>>(x_in, E2in, B_pre);
  uft_kernel<<<512, 256, 0, stream>>>(u, E2in, B_pre, P);
  prep2_kernel<<<512, 256, 0, stream>>>(x_out, E1out, E2out);
  apply_kernel<<<dim3(32, 8), 512, 0, stream>>>(t, w_freq, b_freq, w1, w2, P, A32);
  inv_kernel<<<512, 256, 0, stream>>>(A32, E1out, E2out, Y);
}

// Round 7
// 100.969 us; speedup vs baseline: 1.8809x; 1.0726x over previous
//
#include <hip/hip_runtime.h>
#include <hip/hip_bf16.h>

// SpectralConv2d: B=8, CIN=COUT=32, N=4096, modes 32x x 31y (u_ft needs y 0..15 only)
// Complex-K GEMM formulation (r6 math, passing at absmax 0.00195):
//   u_ft[c,x](y) = sum_k A_y[c,k]*B[k,j]   k=2n+comp, j=2x+comp
//   Y[c,n] = sum_y Re( (sum_j A32_y[c,j]*Bg[j,n]) * E2out[n,y] )
//
// r7 changes (spill elimination — r6 inv wrote 30 MB of scratch at VGPR=128):
//   - inv: no prefetch/rotation (working set ~92 VGPR < 128 step), unroll 1.
//   - uft: NO LDS, NO barriers. A-fragments built in registers directly (the
//     n-quad a thread loads IS its fragment's k-slice), B-fragments read from
//     L2-hot linear B_pre. A-build duplicated across 4 waves (cheap VALU).
//
// ws (u32 slots), 18.0 MB total (proven size):
//   E2in  [8][16][4096]           : 524288    (aliased by A32 after uft)
//   B_pre [8][64ch][64j][64dw]    : 2097152   (aliased by E1out+E2out after uft)
//   P     [8s][8b][16y][32c][64j] : 2097152 f32

#define NPTS 4096
#define TDIM 128
#define TWO_PI 6.283185307179586f

typedef __attribute__((ext_vector_type(8))) short bf16x8;
typedef __attribute__((ext_vector_type(4))) float f32x4;
typedef unsigned int u32;
typedef unsigned short u16;

__device__ __forceinline__ u32 pack2(float a, float b) {
  __hip_bfloat162 h = __float22bfloat162_rn(make_float2(a, b));  // v_cvt_pk_bf16_f32
  u32 r; __builtin_memcpy(&r, &h, 4); return r;
}
__device__ __forceinline__ float bflo(u32 u) { return __uint_as_float(u << 16); }
__device__ __forceinline__ float bfhi(u32 u) { return __uint_as_float(u & 0xFFFF0000u); }
__device__ __forceinline__ bf16x8 as_frag(uint4 v) {
  bf16x8 f; __builtin_memcpy(&f, &v, 16); return f;
}

// ---------------------------------------------------------------------------
// prep1: E2in (y 0..15, k2y=y) + B_pre (conj(E1in)), LINEAR layout (no swizzle —
// uft reads B from global now, no LDS banks involved).
// B_pre[(b*64+nt)*4096 + j*64 + n]:  j=2x -> (c,s) ; j=2x+1 -> (-s,c)
__global__ __launch_bounds__(256) void prep1_kernel(
    const float* __restrict__ x_in, u32* __restrict__ E2in, u32* __restrict__ B_pre) {
  const int bid = blockIdx.x;              // 512
  const int b = bid & 7, ntile = bid >> 3; // 0..63
  const int tid = threadIdx.x;
  const int nl = tid & 63, task = tid >> 6;
  const int n = ntile * 64 + nl;
  float2 xv = *(const float2*)&x_in[(size_t)(b * NPTS + n) * 2];
  if (task < 2) {
    #pragma unroll
    for (int k = 0; k < 8; ++k) {
      int y = task * 8 + k;                          // 0..15 -> k2y = y
      float th = TWO_PI * xv.y * (float)y;
      float s, c; __sincosf(th, &s, &c);
      E2in[((b * 16 + y) << 12) + n] = pack2(c, s);
    }
  } else {
    u32* base = B_pre + (size_t)(b * 64 + ntile) * 4096;
    #pragma unroll
    for (int k = 0; k < 16; ++k) {
      int x = (task - 2) * 16 + k;
      float k1x = (x < 16) ? (float)x : (float)(x - 32);
      float th = TWO_PI * xv.x * k1x;
      float s, c; __sincosf(th, &s, &c);
      base[(2 * x) * 64 + nl]     = pack2(c, s);
      base[(2 * x + 1) * 64 + nl] = pack2(-s, c);
    }
  }
}

// ---------------------------------------------------------------------------
// prep2 (after uft, overwrites B_pre region): E1out + E2out cis tables.
__global__ __launch_bounds__(256) void prep2_kernel(
    const float* __restrict__ x_out, u32* __restrict__ E1out, u32* __restrict__ E2out) {
  const int bid = blockIdx.x;              // 512
  const int b = bid & 7, ntile = bid >> 3;
  const int tid = threadIdx.x;
  const int nl = tid & 63, task = tid >> 6;
  const int n = ntile * 64 + nl;
  float2 xv = *(const float2*)&x_out[(size_t)(b * NPTS + n) * 2];
  if (task < 2) {
    int cnt = task ? 15 : 16;
    for (int k = 0; k < cnt; ++k) {
      int y = task * 16 + k;                         // 0..30
      float k2y = (y < 16) ? (float)y : (float)(y - 31);
      float th = TWO_PI * xv.y * k2y;
      float s, c; __sincosf(th, &s, &c);
      E2out[((b * 32 + y) << 12) + n] = pack2(c, s);
    }
  } else {
    #pragma unroll
    for (int k = 0; k < 16; ++k) {
      int x = (task - 2) * 16 + k;
      float k1x = (x < 16) ? (float)x : (float)(x - 32);
      float th = TWO_PI * xv.x * k1x;
      float s, c; __sincosf(th, &s, &c);
      E1out[((b * 32 + x) << 12) + n] = pack2(c, s);
    }
  }
}

// ---------------------------------------------------------------------------
// uft: grid 512 = (b, yp 0..7, s 0..7). No LDS, no barriers.
// Thread (colw, kq, wv): A-frags for c = colw/colw+16, y = 2yp/2yp+1 built in
// regs from u (coalesced float4) x conj(E2) (wave-broadcast uint4);
// B-frag for j-row brow read from L2-hot B_pre.
__global__ __launch_bounds__(256) void uft_kernel(
    const float* __restrict__ u, const u32* __restrict__ E2in,
    const u32* __restrict__ B_pre, float* __restrict__ P) {
  const int bid = blockIdx.x;
  const int b = bid & 7;                   // XCD pin
  const int inner = bid >> 3;
  const int yp = inner & 7;
  const int s = inner >> 3;
  const int tid = threadIdx.x;
  const int lane = tid & 63, wv = tid >> 6;

  const int y0 = 2 * yp, y1 = 2 * yp + 1;
  const int colw = lane & 15, kq = lane >> 4;
  const int brow = wv * 16 + colw;

  const float* u0p = &u[(size_t)(b * 32 + colw) * NPTS];
  const float* u1p = &u[(size_t)(b * 32 + colw + 16) * NPTS];
  const u32* e0p = &E2in[(b * 16 + y0) << 12];
  const u32* e1p = &E2in[(b * 16 + y1) << 12];
  const u32* bp  = B_pre + (size_t)(b * 64 + s * 8) * 4096 + brow * 64 + kq * 4;

  f32x4 acc00 = {0,0,0,0}, acc01 = {0,0,0,0}, acc10 = {0,0,0,0}, acc11 = {0,0,0,0};

  #pragma unroll 1
  for (int ch = 0; ch < 8; ++ch) {
    const int nq0 = s * 512 + ch * 64 + kq * 4;
    #pragma unroll
    for (int ks = 0; ks < 4; ++ks) {
      const int nq = nq0 + ks * 16;
      float4 uv0 = *(const float4*)(u0p + nq);
      float4 uv1 = *(const float4*)(u1p + nq);
      uint4 e0 = *(const uint4*)(e0p + nq);
      uint4 e1 = *(const uint4*)(e1p + nq);
      uint4 bb = *(const uint4*)(bp + (size_t)ch * 4096 + ks * 16);

      const float uu0[4] = {uv0.x, uv0.y, uv0.z, uv0.w};
      const float uu1[4] = {uv1.x, uv1.y, uv1.z, uv1.w};
      const u32 ee0[4] = {e0.x, e0.y, e0.z, e0.w};
      const u32 ee1[4] = {e1.x, e1.y, e1.z, e1.w};
      u32 w00[4], w01[4], w10[4], w11[4];
      #pragma unroll
      for (int i = 0; i < 4; ++i) {
        float c0v = bflo(ee0[i]), s0v = bfhi(ee0[i]);
        float c1v = bflo(ee1[i]), s1v = bfhi(ee1[i]);
        w00[i] = pack2(uu0[i] * c0v, -(uu0[i] * s0v));   // A(c=colw,   y0)
        w01[i] = pack2(uu1[i] * c0v, -(uu1[i] * s0v));   // A(c=colw+16,y0)
        w10[i] = pack2(uu0[i] * c1v, -(uu0[i] * s1v));   // A(c=colw,   y1)
        w11[i] = pack2(uu1[i] * c1v, -(uu1[i] * s1v));   // A(c=colw+16,y1)
      }
      bf16x8 fb = as_frag(bb);
      acc00 = __builtin_amdgcn_mfma_f32_16x16x32_bf16(
                  as_frag(make_uint4(w00[0], w00[1], w00[2], w00[3])), fb, acc00, 0, 0, 0);
      acc01 = __builtin_amdgcn_mfma_f32_16x16x32_bf16(
                  as_frag(make_uint4(w01[0], w01[1], w01[2], w01[3])), fb, acc01, 0, 0, 0);
      acc10 = __builtin_amdgcn_mfma_f32_16x16x32_bf16(
                  as_frag(make_uint4(w10[0], w10[1], w10[2], w10[3])), fb, acc10, 0, 0, 0);
      acc11 = __builtin_amdgcn_mfma_f32_16x16x32_bf16(
                  as_frag(make_uint4(w11[0], w11[1], w11[2], w11[3])), fb, acc11, 0, 0, 0);
    }
  }

  // P[s][b][y][c][j]
  size_t base0 = (((size_t)s * 8 + b) * 16 + y0) * 2048;
  size_t base1 = (((size_t)s * 8 + b) * 16 + y1) * 2048;
  #pragma unroll
  for (int r = 0; r < 4; ++r) {
    int cr0 = kq * 4 + r, cr1 = cr0 + 16;
    P[base0 + cr0 * 64 + brow] = acc00[r];
    P[base0 + cr1 * 64 + brow] = acc01[r];
    P[base1 + cr0 * 64 + brow] = acc10[r];
    P[base1 + cr1 * 64 + brow] = acc11[r];
  }
}

// ---------------------------------------------------------------------------
// apply: 8-way split-K reduce + emb conditioning + Hermitian extension,
// writes bf16-packed A32[b][y0..30][c][j=2X+comp] (u32 = one complex).
__global__ __launch_bounds__(512) void apply_kernel(
    const float* __restrict__ t, const float* __restrict__ w_freq,
    const float* __restrict__ b_freq, const float* __restrict__ w1,
    const float* __restrict__ w2, const float* __restrict__ P,
    u32* __restrict__ A32) {
  const int x = blockIdx.x, b = blockIdx.y;
  const int tid = threadIdx.x;
  const int m1 = x & 15, sel = x >> 4;

  __shared__ float uf_s[32][16][2];
  __shared__ float emb_s[16][2];

  for (int e = tid; e < 1024; e += 512) {
    int i = e >> 5, r = e & 31, yy = r >> 1, comp = r & 1;
    size_t base = (((size_t)(b * 16 + yy)) * 32 + i) * 64 + 2 * x + comp;
    float sacc = 0.f;
    #pragma unroll
    for (int ss = 0; ss < 8; ++ss) sacc += P[base + (size_t)ss * 262144];
    uf_s[i][yy][comp] = sacc;
  }
  if (tid < 32) {
    int yy = tid >> 1, p = tid & 1;
    int jj = ((m1 * 16 + yy) * 2 + sel) * 2 + p;
    float sv = b_freq[jj];
    for (int k = 0; k < TDIM; ++k) sv += t[b * TDIM + k] * w_freq[k * 1024 + jj];
    emb_s[yy][p] = sv;
  }
  __syncthreads();

  int o = tid >> 4, y = tid & 15;
  const float* wsel = sel ? w2 : w1;
  float fr = 0.f, fi = 0.f;
  #pragma unroll 4
  for (int i = 0; i < 32; ++i) {
    float2 w = *(const float2*)&wsel[(size_t)(((i * 32 + o) * 16 + m1) * 16 + y) * 2];
    float ur = uf_s[i][y][0], ui = uf_s[i][y][1];
    fr += ur * w.x - ui * w.y;
    fi += ur * w.y + ui * w.x;
  }
  float er = emb_s[y][0], ei = emb_s[y][1];
  float orr = fr * er - fi * ei;
  float oii = fr * ei + fi * er;
  A32[((b * 31 + y) * 32 + o) * 32 + x] = pack2(orr, oii);
  if (y > 0)
    A32[((b * 31 + (31 - y)) * 32 + o) * 32 + (31 - x)] = pack2(orr, -oii);
}

// ---------------------------------------------------------------------------
// inv: grid 512 = (b, nt 0..63). B (E1out-derived) in regs for whole y-loop;
// A-frags direct from global (L2-hot) with NO prefetch/rotation — working set
// ~92 VGPR stays under the 128 occupancy step (r6: prefetch pushed it to 124
// -> allocator clamped to 128 and spilled 30 MB of scratch).
__global__ __launch_bounds__(256) void inv_kernel(
    const u32* __restrict__ A32, const u32* __restrict__ E1out,
    const u32* __restrict__ E2out, float* __restrict__ Y) {
  const int bid = blockIdx.x;
  const int b = bid & 7, nt = bid >> 3;
  const int n0 = nt * 64;
  const int tid = threadIdx.x;
  const int lane = tid & 63, wv = tid >> 6;
  const int colw = lane & 15, kq = lane >> 4;

  __shared__ __align__(16) u16 Bgr[64 * 64];   // [n][k=2X+comp] rows 128B, swizzled
  __shared__ __align__(16) u16 Bgi[64 * 64];
  __shared__ u32 e2s[31 * 64];

  {
    const int n = tid & 63, Xg = tid >> 6;
    #pragma unroll
    for (int i = 0; i < 8; ++i) {
      int X = Xg * 8 + i;
      u32 e = E1out[((b * 32 + X) << 12) + n0 + n];
      float c1 = bflo(e), s1 = bfhi(e);
      int byt = (4 * X) ^ ((n & 7) << 4);
      *(u32*)((char*)Bgr + n * 128 + byt) = pack2(c1, -s1);
      *(u32*)((char*)Bgi + n * 128 + byt) = pack2(s1, c1);
    }
  }
  for (int idx = tid; idx < 1984; idx += 256) {
    int y = idx >> 6, n = idx & 63;
    e2s[idx] = E2out[((b * 32 + y) << 12) + n0 + n];
  }
  __syncthreads();

  const int brow = wv * 16 + colw;
  bf16x8 bgr[2], bgi[2];
  #pragma unroll
  for (int ks = 0; ks < 2; ++ks) {
    int kb = ks * 64 + kq * 16;
    bgr[ks] = *(bf16x8*)((char*)Bgr + brow * 128 + (kb ^ ((brow & 7) << 4)));
    bgi[ks] = *(bf16x8*)((char*)Bgi + brow * 128 + (kb ^ ((brow & 7) << 4)));
  }

  f32x4 Y0 = {0,0,0,0}, Y1 = {0,0,0,0};
  const u32* Abase = A32 + (size_t)b * 31 * 1024;

  #pragma unroll 1
  for (int y = 0; y < 31; ++y) {
    const u32* p = Abase + y * 1024;
    bf16x8 af0 = *(bf16x8*)(p + colw * 32 + kq * 4);
    bf16x8 af1 = *(bf16x8*)(p + colw * 32 + 16 + kq * 4);
    bf16x8 af2 = *(bf16x8*)(p + (colw + 16) * 32 + kq * 4);
    bf16x8 af3 = *(bf16x8*)(p + (colw + 16) * 32 + 16 + kq * 4);
    f32x4 z = {0,0,0,0};
    f32x4 gr0 = __builtin_amdgcn_mfma_f32_16x16x32_bf16(af0, bgr[0], z, 0, 0, 0);
    gr0 = __builtin_amdgcn_mfma_f32_16x16x32_bf16(af1, bgr[1], gr0, 0, 0, 0);
    f32x4 gr1 = __builtin_amdgcn_mfma_f32_16x16x32_bf16(af2, bgr[0], z, 0, 0, 0);
    gr1 = __builtin_amdgcn_mfma_f32_16x16x32_bf16(af3, bgr[1], gr1, 0, 0, 0);
    f32x4 gi0 = __builtin_amdgcn_mfma_f32_16x16x32_bf16(af0, bgi[0], z, 0, 0, 0);
    gi0 = __builtin_amdgcn_mfma_f32_16x16x32_bf16(af1, bgi[1], gi0, 0, 0, 0);
    f32x4 gi1 = __builtin_amdgcn_mfma_f32_16x16x32_bf16(af2, bgi[0], z, 0, 0, 0);
    gi1 = __builtin_amdgcn_mfma_f32_16x16x32_bf16(af3, bgi[1], gi1, 0, 0, 0);
    u32 e2 = e2s[y * 64 + brow];
    float c2 = bflo(e2), s2 = bfhi(e2);
    #pragma unroll
    for (int r = 0; r < 4; ++r) {
      Y0[r] += gr0[r] * c2 - gi0[r] * s2;
      Y1[r] += gr1[r] * c2 - gi1[r] * s2;
    }
  }

  int n = n0 + brow;
  #pragma unroll
  for (int r = 0; r < 4; ++r) {
    Y[(size_t)(b * 32 + kq * 4 + r) * NPTS + n] = Y0[r];
    Y[(size_t)(b * 32 + kq * 4 + r + 16) * NPTS + n] = Y1[r];
  }
}

// ---------------------------------------------------------------------------
extern "C" void kernel_launch(void* const* d_in, const int* in_sizes, int n_in,
                              void* d_out, int out_size, void* d_ws, size_t ws_size,
                              hipStream_t stream) {
  const float* u      = (const float*)d_in[0];
  const float* x_in   = (const float*)d_in[1];
  const float* x_out  = (const float*)d_in[2];
  const float* t      = (const float*)d_in[3];
  const float* w_freq = (const float*)d_in[4];
  const float* b_freq = (const float*)d_in[5];
  const float* w1     = (const float*)d_in[6];
  const float* w2     = (const float*)d_in[7];
  float* Y = (float*)d_out;

  u32* E2in  = (u32*)d_ws;                 // 524288
  u32* B_pre = E2in + 524288;              // 2097152
  u32* E1out = B_pre;                      // alias (prep2 runs after uft)
  u32* E2out = B_pre + 1048576;
  float* P   = (float*)(B_pre + 2097152);  // 2097152 f32
  u32* A32   = E2in;                       // alias (apply runs after uft)

  prep1_kernel<<<512, 256, 0, stream>>>(x_in, E2in, B_pre);
  uft_kernel<<<512, 256, 0, stream>>>(u, E2in, B_pre, P);
  prep2_kernel<<<512, 256, 0, stream>>>(x_out, E1out, E2out);
  apply_kernel<<<dim3(32, 8), 512, 0, stream>>>(t, w_freq, b_freq, w1, w2, P, A32);
  inv_kernel<<<512, 256, 0, stream>>>(A32, E1out, E2out, Y);
}